// Round 15
// baseline (1278.507 us; speedup 1.0000x reference)
//
#include <hip/hip_runtime.h>
#include <hip/hip_fp16.h>
#include <hip/hip_cooperative_groups.h>
#include <math.h>

namespace cg = cooperative_groups;

static constexpr float BN_EPS = 1e-5f;
static constexpr float NEG = 0.2f;

typedef float f32x4 __attribute__((ext_vector_type(4)));
typedef _Float16 h16x2 __attribute__((ext_vector_type(2)));
typedef _Float16 h16x8 __attribute__((ext_vector_type(8)));

// ---------------- cooperative CSR build: one kernel, 6 phases ----------------
// Replaces memset x2 + hist + scan_block + scan_bsums + scan_add + scatter
// (7 graph nodes -> 1). Chunk size 256; nc = ceil(n/256) must be <= 256
// (n = 50000 -> nc = 196, ok).

__global__ __launch_bounds__(256) void csr_build(
    const int* __restrict__ ei, int E, int n,
    int* __restrict__ cnt, int* __restrict__ fill,
    int* __restrict__ rowptr, int* __restrict__ col,
    int* __restrict__ bsums, int nc) {
    cg::grid_group grid = cg::this_grid();
    const int tid = blockIdx.x * blockDim.x + threadIdx.x;
    const int nthreads = gridDim.x * blockDim.x;
    const int ET = E + n;
    __shared__ int s[256];

    // P0: zero counters
    for (int i = tid; i < n; i += nthreads) { cnt[i] = 0; fill[i] = 0; }
    grid.sync();

    // P1: histogram of dst (self-loop for e >= E)
    for (int e = tid; e < ET; e += nthreads) {
        int d = (e < E) ? ei[E + e] : (e - E);
        atomicAdd(&cnt[d], 1);
    }
    grid.sync();

    // P2: per-256-chunk inclusive scan -> rowptr[i+1], chunk totals -> bsums
    for (int c = blockIdx.x; c < nc; c += gridDim.x) {
        int i = c * 256 + threadIdx.x;
        int v = (i < n) ? cnt[i] : 0;
        s[threadIdx.x] = v;
        __syncthreads();
        for (int d = 1; d < 256; d <<= 1) {
            int t = (threadIdx.x >= d) ? s[threadIdx.x - d] : 0;
            __syncthreads();
            s[threadIdx.x] += t;
            __syncthreads();
        }
        if (i < n) rowptr[i + 1] = s[threadIdx.x];
        if (threadIdx.x == 255) bsums[c] = s[255];
        __syncthreads();
    }
    grid.sync();

    // P3: exclusive scan of bsums (nc <= 256), block 0 only
    if (blockIdx.x == 0) {
        int L = threadIdx.x;
        s[L] = (L < nc) ? bsums[L] : 0;
        __syncthreads();
        for (int d = 1; d < 256; d <<= 1) {
            int t = (L >= d) ? s[L - d] : 0;
            __syncthreads();
            s[L] += t;
            __syncthreads();
        }
        int ex = (L == 0) ? 0 : s[L - 1];
        if (L < nc) bsums[L] = ex;
    }
    grid.sync();

    // P4: add chunk prefixes
    for (int i = tid; i < n; i += nthreads) rowptr[i + 1] += bsums[i >> 8];
    if (tid == 0) rowptr[0] = 0;
    grid.sync();

    // P5: scatter src into col
    for (int e = tid; e < ET; e += nthreads) {
        int sv, d;
        if (e < E) { sv = ei[e]; d = ei[E + e]; } else { sv = e - E; d = sv; }
        int pos = atomicAdd(&fill[d], 1);
        col[rowptr[d] + pos] = sv;
    }
}

// ---------------- fused W packing (all 4 layers, one launch) ----------------

__global__ void pack_all(const float* __restrict__ W0l, const float* __restrict__ W0r,
                         const float* __restrict__ W1l, const float* __restrict__ W1r,
                         const float* __restrict__ W2l, const float* __restrict__ W2r,
                         const float* __restrict__ W3l, const float* __restrict__ W3r,
                         __half* __restrict__ pk0, __half* __restrict__ pk1,
                         __half* __restrict__ pk2, __half* __restrict__ pk3) {
    int b = blockIdx.x;
    const float *Wl, *Wr;
    __half* packed;
    int tile, NTT, M;
    if (b < 192) {
        int layer = b >> 6;
        tile = b & 63;
        NTT = 16; M = 128;
        Wl = (layer == 0) ? W0l : (layer == 1) ? W1l : W2l;
        Wr = (layer == 0) ? W0r : (layer == 1) ? W1r : W2r;
        packed = (layer == 0) ? pk0 : (layer == 1) ? pk1 : pk2;
    } else {
        tile = b - 192;
        NTT = 2; M = 16;
        Wl = W3l; Wr = W3r; packed = pk3;
    }
    int NT = NTT >> 1;
    int gnt = tile % NTT;
    int kt = tile / NTT;
    int l = threadIdx.x;               // 64
    const float* W = (gnt < NT) ? Wl : Wr;
    int col = (gnt % NT) * 16 + (l & 15);
    int krow = kt * 32 + ((l >> 4) << 3);
    size_t base = (size_t)tile * 512 + (size_t)l * 8;
#pragma unroll
    for (int j = 0; j < 8; j++)
        packed[base + j] = __float2half(W[(size_t)(krow + j) * M + col]);
}

// ---------------- fp16 MFMA dual GEMM: Y1 = X@Wl, Y2 = X@Wr (M=128 each) ----

template <bool FIRST>
__global__ __launch_bounds__(256) void gemm_h_big(
    const __half* __restrict__ xh, const float* __restrict__ xf,
    const __half* __restrict__ packed,
    __half* __restrict__ Y1, __half* __restrict__ Y2, int n) {
    __shared__ _Float16 sA[64 * 136];
    const int t = threadIdx.x;
    const int row0 = blockIdx.x * 64;

    for (int c = t; c < 1024; c += 256) {
        int row = c >> 4;
        int off = (c & 15) * 8;
        int gr = row0 + row;
        if (gr >= n) gr = n - 1;
        if (FIRST) {
            float4 v0 = *(const float4*)&xf[(size_t)gr * 128 + off];
            float4 v1 = *(const float4*)&xf[(size_t)gr * 128 + off + 4];
            h16x8 h = {(_Float16)v0.x, (_Float16)v0.y, (_Float16)v0.z, (_Float16)v0.w,
                       (_Float16)v1.x, (_Float16)v1.y, (_Float16)v1.z, (_Float16)v1.w};
            *(h16x8*)&sA[row * 136 + off] = h;
        } else {
            *(h16x8*)&sA[row * 136 + off] = *(const h16x8*)&xh[(size_t)gr * 128 + off];
        }
    }
    __syncthreads();

    const int lane = t & 63;
    const int s = t >> 6;
    const int lr = lane & 15;
    const int kq = (lane >> 4) * 8;

    h16x8 af[4][4];                 // [rt][kt]
#pragma unroll
    for (int rt = 0; rt < 4; rt++)
#pragma unroll
        for (int kt = 0; kt < 4; kt++)
            af[rt][kt] = *(const h16x8*)&sA[(rt * 16 + lr) * 136 + kt * 32 + kq];

    f32x4 acc[4][4];                // [ntl][rt]
#pragma unroll
    for (int a = 0; a < 4; a++)
#pragma unroll
        for (int b = 0; b < 4; b++) acc[a][b] = (f32x4){0.f, 0.f, 0.f, 0.f};

#pragma unroll
    for (int kt = 0; kt < 4; kt++) {
#pragma unroll
        for (int ntl = 0; ntl < 4; ntl++) {
            int nt = s * 4 + ntl;
            h16x8 b = *(const h16x8*)&packed[((size_t)(kt * 16 + nt)) * 512 + lane * 8];
#pragma unroll
            for (int rt = 0; rt < 4; rt++)
                acc[ntl][rt] = __builtin_amdgcn_mfma_f32_16x16x32_f16(af[rt][kt], b, acc[ntl][rt], 0, 0, 0);
        }
    }

    __half* Y = (s < 2) ? Y1 : Y2;
    const int colh = (s & 1) * 64;
    const int rq = (lane >> 4) * 4;
#pragma unroll
    for (int ntl = 0; ntl < 4; ntl++) {
        int col = colh + ntl * 16 + lr;
#pragma unroll
        for (int rt = 0; rt < 4; rt++) {
#pragma unroll
            for (int g = 0; g < 4; g++) {
                int row = row0 + rt * 16 + rq + g;
                if (row < n) Y[(size_t)row * 128 + col] = __float2half(acc[ntl][rt][g]);
            }
        }
    }
}

// ---------------- small fp16 GEMM for layer 3 (M=16 each, fp32 out) ----------

__global__ __launch_bounds__(256) void gemm_h_small(
    const __half* __restrict__ xh, const __half* __restrict__ packed,
    float* __restrict__ Y1, float* __restrict__ Y2, int n) {
    int lane = threadIdx.x & 63;
    int wv = blockIdx.x * 4 + (threadIdx.x >> 6);
    int row0 = wv * 16;
    if (row0 >= n) return;
    int r = row0 + (lane & 15);
    if (r >= n) r = n - 1;
    int kq = (lane >> 4) * 8;

    h16x8 af[4];
#pragma unroll
    for (int kt = 0; kt < 4; kt++)
        af[kt] = *(const h16x8*)&xh[(size_t)r * 128 + kt * 32 + kq];

    f32x4 acc[2];
    acc[0] = (f32x4){0.f, 0.f, 0.f, 0.f};
    acc[1] = (f32x4){0.f, 0.f, 0.f, 0.f};

#pragma unroll
    for (int kt = 0; kt < 4; kt++) {
#pragma unroll
        for (int nt = 0; nt < 2; nt++) {
            h16x8 b = *(const h16x8*)&packed[((size_t)(kt * 2 + nt)) * 512 + lane * 8];
            acc[nt] = __builtin_amdgcn_mfma_f32_16x16x32_f16(af[kt], b, acc[nt], 0, 0, 0);
        }
    }

    int colb = lane & 15;
    int rbase = row0 + (lane >> 4) * 4;
#pragma unroll
    for (int nt = 0; nt < 2; nt++) {
        float* Y = (nt == 0) ? Y1 : Y2;
#pragma unroll
        for (int g = 0; g < 4; g++) {
            int row = rbase + g;
            if (row < n) Y[(size_t)row * 16 + colb] = acc[nt][g];
        }
    }
}

// ---------------- Fused GATv2 aggregate (R11-proven 2-edge form) ------------

__device__ __forceinline__ float dot4_h(h16x2 l01, h16x2 l23,
                                        h16x2 a01, h16x2 a23) {
#if __has_builtin(__builtin_amdgcn_fdot2)
    float part = __builtin_amdgcn_fdot2(l01, a01, 0.f, false);
    return __builtin_amdgcn_fdot2(l23, a23, part, false);
#else
    return fmaf((float)l01.x, (float)a01.x, fmaf((float)l01.y, (float)a01.y,
           fmaf((float)l23.x, (float)a23.x, (float)l23.y * (float)a23.y)));
#endif
}

__global__ __launch_bounds__(256) void agg_h(
    const __half* __restrict__ xl, const __half* __restrict__ xr,
    const int* __restrict__ rowptr, const int* __restrict__ col,
    const float* __restrict__ att, const float* __restrict__ bias,
    const float* __restrict__ g, const float* __restrict__ be,
    const float* __restrict__ bm, const float* __restrict__ bv,
    __half* __restrict__ oh, int n) {
    int v = (blockIdx.x * blockDim.x + threadIdx.x) >> 6;
    if (v >= n) return;
    int lane = threadIdx.x & 63;
    int half = lane >> 5;
    int L = lane & 31;
    int ch = 4 * L;

    float2 rraw = *(const float2*)&xr[(size_t)v * 128 + ch];
    h16x2 rx01 = *(h16x2*)&rraw.x;
    h16x2 rx23 = *(h16x2*)&rraw.y;
    float4 av = *(const float4*)&att[ch];
    h16x2 a01 = {(_Float16)av.x, (_Float16)av.y};
    h16x2 a23 = {(_Float16)av.z, (_Float16)av.w};
    const h16x2 neg2 = {(_Float16)NEG, (_Float16)NEG};

    int beg = rowptr[v];
    int end = rowptr[v + 1];

    float lrun = 0.f;
    float4 acc = make_float4(0.f, 0.f, 0.f, 0.f);

    auto proc = [&](float2 raw, bool ok) {
        h16x2 h01 = *(h16x2*)&raw.x;
        h16x2 h23 = *(h16x2*)&raw.y;
        h16x2 s01 = h01 + rx01;
        h16x2 s23 = h23 + rx23;
        h16x2 l01 = __builtin_elementwise_max(s01, s01 * neg2);
        h16x2 l23 = __builtin_elementwise_max(s23, s23 * neg2);
        float part = dot4_h(l01, l23, a01, a23);
        part += __shfl_xor(part, 1);
        part += __shfl_xor(part, 2);
        float p = ok ? __expf(part) : 0.f;
        lrun += p;
        acc.x = fmaf(p, (float)h01.x, acc.x);
        acc.y = fmaf(p, (float)h01.y, acc.y);
        acc.z = fmaf(p, (float)h23.x, acc.z);
        acc.w = fmaf(p, (float)h23.y, acc.w);
    };

    int e = beg;
    for (; e + 8 <= end; e += 8) {      // full batches: no masking at all
        float2 r[4];
#pragma unroll
        for (int j = 0; j < 4; j++) {
            int u = col[e + 2 * j + half];
            r[j] = *(const float2*)&xl[((size_t)u << 7) + ch];
        }
#pragma unroll
        for (int j = 0; j < 4; j++) proc(r[j], true);
    }
    for (; e < end; e += 4) {           // masked tail, 4-edge granularity
        float2 r[2];
        bool ok[2];
#pragma unroll
        for (int j = 0; j < 2; j++) {
            int idx = e + 2 * j + half;
            ok[j] = (idx < end);
            r[j] = make_float2(0.f, 0.f);
            if (ok[j]) {
                int u = col[idx];
                r[j] = *(const float2*)&xl[((size_t)u << 7) + ch];
            }
        }
#pragma unroll
        for (int j = 0; j < 2; j++) proc(r[j], ok[j]);
    }

    // combine the two 32-lane halves
    lrun += __shfl_xor(lrun, 32);
    acc.x += __shfl_xor(acc.x, 32);
    acc.y += __shfl_xor(acc.y, 32);
    acc.z += __shfl_xor(acc.z, 32);
    acc.w += __shfl_xor(acc.w, 32);

    if (half == 0) {
        float inv = 1.0f / lrun;
        float4 b4 = *(const float4*)&bias[ch];
        float o[4] = {fmaf(acc.x, inv, b4.x), fmaf(acc.y, inv, b4.y),
                      fmaf(acc.z, inv, b4.z), fmaf(acc.w, inv, b4.w)};
        float4 m4 = *(const float4*)&bm[ch];
        float4 v4 = *(const float4*)&bv[ch];
        float4 g4 = *(const float4*)&g[ch];
        float4 e4 = *(const float4*)&be[ch];
        float ms[4] = {m4.x, m4.y, m4.z, m4.w};
        float vs[4] = {v4.x, v4.y, v4.z, v4.w};
        float gs[4] = {g4.x, g4.y, g4.z, g4.w};
        float es[4] = {e4.x, e4.y, e4.z, e4.w};
        unsigned short h[4];
#pragma unroll
        for (int j = 0; j < 4; j++) {
            o[j] = (o[j] - ms[j]) * rsqrtf(vs[j] + BN_EPS) * gs[j] + es[j];
            o[j] = o[j] > 0.f ? o[j] : expm1f(o[j]);
            h[j] = __half_as_ushort(__float2half(o[j]));
        }
        *(ushort4*)&oh[(size_t)v * 128 + ch] = make_ushort4(h[0], h[1], h[2], h[3]);
    }
}

// ---------------- final aggregate, fp32, HC=16, writes d_out ----------------

__global__ __launch_bounds__(256) void agg_f(
    const float* __restrict__ xl, const float* __restrict__ xr,
    const int* __restrict__ rowptr, const int* __restrict__ col,
    const float* __restrict__ att, const float* __restrict__ bias,
    float* __restrict__ out, int n) {
    int v = (blockIdx.x * blockDim.x + threadIdx.x) >> 6;
    if (v >= n) return;
    int lane = threadIdx.x & 63;
    int slot = lane >> 2;        // 16 edge slots
    int L = lane & 3;
    int ch = 4 * L;

    float4 xrv = *(const float4*)&xr[(size_t)v * 16 + ch];
    float4 av = *(const float4*)&att[ch];
    int beg = rowptr[v];
    int end = rowptr[v + 1];

    float lrun = 0.f;
    float4 acc = make_float4(0.f, 0.f, 0.f, 0.f);

    for (int eb = beg; eb < end; eb += 16) {
        int idx = eb + slot;
        bool ok = (idx < end);
        float4 xv = make_float4(0.f, 0.f, 0.f, 0.f);
        if (ok) {
            int u = col[idx];
            xv = *(const float4*)&xl[((size_t)u << 4) + ch];
        }
        float s0 = xv.x + xrv.x; s0 = s0 > 0.f ? s0 : NEG * s0;
        float s1 = xv.y + xrv.y; s1 = s1 > 0.f ? s1 : NEG * s1;
        float s2 = xv.z + xrv.z; s2 = s2 > 0.f ? s2 : NEG * s2;
        float s3 = xv.w + xrv.w; s3 = s3 > 0.f ? s3 : NEG * s3;
        float part = fmaf(s0, av.x, fmaf(s1, av.y, fmaf(s2, av.z, s3 * av.w)));
        part += __shfl_xor(part, 1);
        part += __shfl_xor(part, 2);
        float p = ok ? __expf(part) : 0.f;
        lrun += p;
        acc.x = fmaf(p, xv.x, acc.x);
        acc.y = fmaf(p, xv.y, acc.y);
        acc.z = fmaf(p, xv.z, acc.z);
        acc.w = fmaf(p, xv.w, acc.w);
    }

#pragma unroll
    for (int d = 4; d < 64; d <<= 1) {
        lrun += __shfl_xor(lrun, d);
        acc.x += __shfl_xor(acc.x, d);
        acc.y += __shfl_xor(acc.y, d);
        acc.z += __shfl_xor(acc.z, d);
        acc.w += __shfl_xor(acc.w, d);
    }

    if (slot == 0) {
        float inv = 1.0f / lrun;
        float4 b4 = *(const float4*)&bias[ch];
        *(float4*)&out[(size_t)v * 16 + ch] =
            make_float4(fmaf(acc.x, inv, b4.x), fmaf(acc.y, inv, b4.y),
                        fmaf(acc.z, inv, b4.z), fmaf(acc.w, inv, b4.w));
    }
}

// ---------------- launch ----------------

extern "C" void kernel_launch(void* const* d_in, const int* in_sizes, int n_in,
                              void* d_out, int out_size, void* d_ws, size_t ws_size,
                              hipStream_t stream) {
    const float* x = (const float*)d_in[0];
    const int* ei = (const int*)d_in[1];
    const float* Wl[4] = {(const float*)d_in[2], (const float*)d_in[6],
                          (const float*)d_in[10], (const float*)d_in[14]};
    const float* Wr[4] = {(const float*)d_in[3], (const float*)d_in[7],
                          (const float*)d_in[11], (const float*)d_in[15]};
    const float* att[4] = {(const float*)d_in[4], (const float*)d_in[8],
                           (const float*)d_in[12], (const float*)d_in[16]};
    const float* bias[4] = {(const float*)d_in[5], (const float*)d_in[9],
                            (const float*)d_in[13], (const float*)d_in[17]};
    const float* g[3] = {(const float*)d_in[18], (const float*)d_in[22], (const float*)d_in[26]};
    const float* be[3] = {(const float*)d_in[19], (const float*)d_in[23], (const float*)d_in[27]};
    const float* bm[3] = {(const float*)d_in[20], (const float*)d_in[24], (const float*)d_in[28]};
    const float* bv[3] = {(const float*)d_in[21], (const float*)d_in[25], (const float*)d_in[29]};

    const int n = in_sizes[0] / 128;
    const int E = in_sizes[1] / 2;
    const int ET = E + n;

    char* p = (char*)d_ws;
    __half* xh = (__half*)p;           p += (size_t)n * 128 * 2;
    __half* xlh = (__half*)p;          p += (size_t)n * 128 * 2;
    __half* xrh = (__half*)p;          p += (size_t)n * 128 * 2;
    float* xl3 = (float*)p;            p += (size_t)n * 16 * 4;
    float* xr3 = (float*)p;            p += (size_t)n * 16 * 4;
    int* rowptr = (int*)p;            p += (size_t)(n + 1) * 4;
    int* cnt = (int*)p;               p += (size_t)n * 4;
    int* fill = (int*)p;              p += (size_t)n * 4;
    int* col = (int*)p;               p += (size_t)ET * 4;
    int* bsums = (int*)p;             p += 1024;
    __half* pk[4];
    for (int i = 0; i < 3; i++) { pk[i] = (__half*)p; p += 4 * 16 * 512 * 2; }
    pk[3] = (__half*)p;               p += 4 * 2 * 512 * 2;

    // cooperative CSR build: size grid by occupancy, cap at 2048 blocks
    int nc = (n + 255) / 256;
    int blocksPerCU = 0;
    (void)hipOccupancyMaxActiveBlocksPerMultiprocessor(&blocksPerCU, (const void*)csr_build, 256, 0);
    if (blocksPerCU < 1) blocksPerCU = 1;
    int csrGrid = blocksPerCU * 256;          // 256 CUs on MI355X
    if (csrGrid > 2048) csrGrid = 2048;
    int E_ = E, n_ = n, nc_ = nc;
    void* args[] = {(void*)&ei, (void*)&E_, (void*)&n_, (void*)&cnt, (void*)&fill,
                    (void*)&rowptr, (void*)&col, (void*)&bsums, (void*)&nc_};
    (void)hipLaunchCooperativeKernel((const void*)csr_build, dim3(csrGrid), dim3(256),
                                     args, 0, stream);

    pack_all<<<200, 64, 0, stream>>>(Wl[0], Wr[0], Wl[1], Wr[1], Wl[2], Wr[2],
                                     Wl[3], Wr[3], pk[0], pk[1], pk[2], pk[3]);

    const int gb64 = (n + 63) / 64;
    const int gemmBlocksSmall = ((n + 15) / 16 + 3) / 4;
    const int aggBlocks = (n + 3) / 4;    // 1 node per wave, 4 waves/block

    // layer 0: GEMM stages LDS straight from fp32 x (no convert pass)
    gemm_h_big<true><<<gb64, 256, 0, stream>>>(nullptr, x, pk[0], xlh, xrh, n);
    agg_h<<<aggBlocks, 256, 0, stream>>>(
        xlh, xrh, rowptr, col, att[0], bias[0], g[0], be[0], bm[0], bv[0], xh, n);
    for (int i = 1; i < 3; i++) {
        gemm_h_big<false><<<gb64, 256, 0, stream>>>(xh, nullptr, pk[i], xlh, xrh, n);
        agg_h<<<aggBlocks, 256, 0, stream>>>(
            xlh, xrh, rowptr, col, att[i], bias[i], g[i], be[i], bm[i], bv[i], xh, n);
    }
    gemm_h_small<<<gemmBlocksSmall, 256, 0, stream>>>(xh, pk[3], xl3, xr3, n);
    agg_f<<<aggBlocks, 256, 0, stream>>>(
        xl3, xr3, rowptr, col, att[3], bias[3], (float*)d_out, n);
}

// Round 16
// 374.725 us; speedup vs baseline: 3.4119x; 3.4119x over previous
//
#include <hip/hip_runtime.h>
#include <hip/hip_fp16.h>
#include <math.h>

static constexpr float BN_EPS = 1e-5f;
static constexpr float NEG = 0.2f;

typedef float f32x4 __attribute__((ext_vector_type(4)));
typedef _Float16 h16x2 __attribute__((ext_vector_type(2)));
typedef _Float16 h16x8 __attribute__((ext_vector_type(8)));

// ---------------- CSR build (R11-proven path; R15 showed grid.sync costs
// ~190us/barrier at 2048 blocks — kernel boundaries are the cheap barrier) ----

__global__ void hist_kernel(const int* __restrict__ ei, int E, int n, int* __restrict__ cnt) {
    int e = blockIdx.x * blockDim.x + threadIdx.x;
    int ET = E + n;
    if (e >= ET) return;
    int d = (e < E) ? ei[E + e] : (e - E);
    atomicAdd(&cnt[d], 1);
}

__global__ void scan_block(const int* __restrict__ cnt, int* __restrict__ rowptr,
                           int* __restrict__ bsums, int n) {
    __shared__ int s[1024];
    int i = blockIdx.x * 1024 + threadIdx.x;
    int vv = (i < n) ? cnt[i] : 0;
    s[threadIdx.x] = vv;
    __syncthreads();
    for (int d = 1; d < 1024; d <<= 1) {
        int t = (threadIdx.x >= d) ? s[threadIdx.x - d] : 0;
        __syncthreads();
        s[threadIdx.x] += t;
        __syncthreads();
    }
    if (i < n) rowptr[i + 1] = s[threadIdx.x];
    if (threadIdx.x == 1023) bsums[blockIdx.x] = s[1023];
}

__global__ void scan_bsums(int* __restrict__ bsums, int nb) {
    int L = threadIdx.x;
    int v = (L < nb) ? bsums[L] : 0;
    for (int d = 1; d < 64; d <<= 1) {
        int t = __shfl_up(v, d);
        if (L >= d) v += t;
    }
    int ex = __shfl_up(v, 1);
    if (L == 0) ex = 0;
    if (L < nb) bsums[L] = ex;
}

__global__ void scan_add(int* __restrict__ rowptr, const int* __restrict__ bsums, int n) {
    int i = blockIdx.x * 1024 + threadIdx.x;
    if (i < n) rowptr[i + 1] += bsums[blockIdx.x];
    if (i == 0) rowptr[0] = 0;
}

__global__ void scatter_kernel(const int* __restrict__ ei, int E, int n,
                               const int* __restrict__ rowptr, int* __restrict__ fill,
                               int* __restrict__ col) {
    int e = blockIdx.x * blockDim.x + threadIdx.x;
    int ET = E + n;
    if (e >= ET) return;
    int s, d;
    if (e < E) { s = ei[e]; d = ei[E + e]; } else { s = e - E; d = s; }
    int pos = atomicAdd(&fill[d], 1);
    col[rowptr[d] + pos] = s;
}

// ---------------- fused W packing (all 4 layers, one launch) ----------------

__global__ void pack_all(const float* __restrict__ W0l, const float* __restrict__ W0r,
                         const float* __restrict__ W1l, const float* __restrict__ W1r,
                         const float* __restrict__ W2l, const float* __restrict__ W2r,
                         const float* __restrict__ W3l, const float* __restrict__ W3r,
                         __half* __restrict__ pk0, __half* __restrict__ pk1,
                         __half* __restrict__ pk2, __half* __restrict__ pk3) {
    int b = blockIdx.x;
    const float *Wl, *Wr;
    __half* packed;
    int tile, NTT, M;
    if (b < 192) {
        int layer = b >> 6;
        tile = b & 63;
        NTT = 16; M = 128;
        Wl = (layer == 0) ? W0l : (layer == 1) ? W1l : W2l;
        Wr = (layer == 0) ? W0r : (layer == 1) ? W1r : W2r;
        packed = (layer == 0) ? pk0 : (layer == 1) ? pk1 : pk2;
    } else {
        tile = b - 192;
        NTT = 2; M = 16;
        Wl = W3l; Wr = W3r; packed = pk3;
    }
    int NT = NTT >> 1;
    int gnt = tile % NTT;
    int kt = tile / NTT;
    int l = threadIdx.x;               // 64
    const float* W = (gnt < NT) ? Wl : Wr;
    int col = (gnt % NT) * 16 + (l & 15);
    int krow = kt * 32 + ((l >> 4) << 3);
    size_t base = (size_t)tile * 512 + (size_t)l * 8;
#pragma unroll
    for (int j = 0; j < 8; j++)
        packed[base + j] = __float2half(W[(size_t)(krow + j) * M + col]);
}

// ---------------- fp16 MFMA dual GEMM: Y1 = X@Wl, Y2 = X@Wr (M=128 each) ----

template <bool FIRST>
__global__ __launch_bounds__(256) void gemm_h_big(
    const __half* __restrict__ xh, const float* __restrict__ xf,
    const __half* __restrict__ packed,
    __half* __restrict__ Y1, __half* __restrict__ Y2, int n) {
    __shared__ _Float16 sA[64 * 136];
    const int t = threadIdx.x;
    const int row0 = blockIdx.x * 64;

    for (int c = t; c < 1024; c += 256) {
        int row = c >> 4;
        int off = (c & 15) * 8;
        int gr = row0 + row;
        if (gr >= n) gr = n - 1;
        if (FIRST) {
            float4 v0 = *(const float4*)&xf[(size_t)gr * 128 + off];
            float4 v1 = *(const float4*)&xf[(size_t)gr * 128 + off + 4];
            h16x8 h = {(_Float16)v0.x, (_Float16)v0.y, (_Float16)v0.z, (_Float16)v0.w,
                       (_Float16)v1.x, (_Float16)v1.y, (_Float16)v1.z, (_Float16)v1.w};
            *(h16x8*)&sA[row * 136 + off] = h;
        } else {
            *(h16x8*)&sA[row * 136 + off] = *(const h16x8*)&xh[(size_t)gr * 128 + off];
        }
    }
    __syncthreads();

    const int lane = t & 63;
    const int s = t >> 6;
    const int lr = lane & 15;
    const int kq = (lane >> 4) * 8;

    h16x8 af[4][4];                 // [rt][kt]
#pragma unroll
    for (int rt = 0; rt < 4; rt++)
#pragma unroll
        for (int kt = 0; kt < 4; kt++)
            af[rt][kt] = *(const h16x8*)&sA[(rt * 16 + lr) * 136 + kt * 32 + kq];

    f32x4 acc[4][4];                // [ntl][rt]
#pragma unroll
    for (int a = 0; a < 4; a++)
#pragma unroll
        for (int b = 0; b < 4; b++) acc[a][b] = (f32x4){0.f, 0.f, 0.f, 0.f};

#pragma unroll
    for (int kt = 0; kt < 4; kt++) {
#pragma unroll
        for (int ntl = 0; ntl < 4; ntl++) {
            int nt = s * 4 + ntl;
            h16x8 b = *(const h16x8*)&packed[((size_t)(kt * 16 + nt)) * 512 + lane * 8];
#pragma unroll
            for (int rt = 0; rt < 4; rt++)
                acc[ntl][rt] = __builtin_amdgcn_mfma_f32_16x16x32_f16(af[rt][kt], b, acc[ntl][rt], 0, 0, 0);
        }
    }

    __half* Y = (s < 2) ? Y1 : Y2;
    const int colh = (s & 1) * 64;
    const int rq = (lane >> 4) * 4;
#pragma unroll
    for (int ntl = 0; ntl < 4; ntl++) {
        int col = colh + ntl * 16 + lr;
#pragma unroll
        for (int rt = 0; rt < 4; rt++) {
#pragma unroll
            for (int g = 0; g < 4; g++) {
                int row = row0 + rt * 16 + rq + g;
                if (row < n) Y[(size_t)row * 128 + col] = __float2half(acc[ntl][rt][g]);
            }
        }
    }
}

// ---------------- small fp16 GEMM for layer 3 (M=16 each, fp32 out) ----------

__global__ __launch_bounds__(256) void gemm_h_small(
    const __half* __restrict__ xh, const __half* __restrict__ packed,
    float* __restrict__ Y1, float* __restrict__ Y2, int n) {
    int lane = threadIdx.x & 63;
    int wv = blockIdx.x * 4 + (threadIdx.x >> 6);
    int row0 = wv * 16;
    if (row0 >= n) return;
    int r = row0 + (lane & 15);
    if (r >= n) r = n - 1;
    int kq = (lane >> 4) * 8;

    h16x8 af[4];
#pragma unroll
    for (int kt = 0; kt < 4; kt++)
        af[kt] = *(const h16x8*)&xh[(size_t)r * 128 + kt * 32 + kq];

    f32x4 acc[2];
    acc[0] = (f32x4){0.f, 0.f, 0.f, 0.f};
    acc[1] = (f32x4){0.f, 0.f, 0.f, 0.f};

#pragma unroll
    for (int kt = 0; kt < 4; kt++) {
#pragma unroll
        for (int nt = 0; nt < 2; nt++) {
            h16x8 b = *(const h16x8*)&packed[((size_t)(kt * 2 + nt)) * 512 + lane * 8];
            acc[nt] = __builtin_amdgcn_mfma_f32_16x16x32_f16(af[kt], b, acc[nt], 0, 0, 0);
        }
    }

    int colb = lane & 15;
    int rbase = row0 + (lane >> 4) * 4;
#pragma unroll
    for (int nt = 0; nt < 2; nt++) {
        float* Y = (nt == 0) ? Y1 : Y2;
#pragma unroll
        for (int g = 0; g < 4; g++) {
            int row = rbase + g;
            if (row < n) Y[(size_t)row * 16 + colb] = acc[nt][g];
        }
    }
}

// ---------------- Fused GATv2 aggregate (R11-proven 2-edge form) ------------

__device__ __forceinline__ float dot4_h(h16x2 l01, h16x2 l23,
                                        h16x2 a01, h16x2 a23) {
#if __has_builtin(__builtin_amdgcn_fdot2)
    float part = __builtin_amdgcn_fdot2(l01, a01, 0.f, false);
    return __builtin_amdgcn_fdot2(l23, a23, part, false);
#else
    return fmaf((float)l01.x, (float)a01.x, fmaf((float)l01.y, (float)a01.y,
           fmaf((float)l23.x, (float)a23.x, (float)l23.y * (float)a23.y)));
#endif
}

__global__ __launch_bounds__(256) void agg_h(
    const __half* __restrict__ xl, const __half* __restrict__ xr,
    const int* __restrict__ rowptr, const int* __restrict__ col,
    const float* __restrict__ att, const float* __restrict__ bias,
    const float* __restrict__ g, const float* __restrict__ be,
    const float* __restrict__ bm, const float* __restrict__ bv,
    __half* __restrict__ oh, int n) {
    int v = (blockIdx.x * blockDim.x + threadIdx.x) >> 6;
    if (v >= n) return;
    int lane = threadIdx.x & 63;
    int half = lane >> 5;
    int L = lane & 31;
    int ch = 4 * L;

    float2 rraw = *(const float2*)&xr[(size_t)v * 128 + ch];
    h16x2 rx01 = *(h16x2*)&rraw.x;
    h16x2 rx23 = *(h16x2*)&rraw.y;
    float4 av = *(const float4*)&att[ch];
    h16x2 a01 = {(_Float16)av.x, (_Float16)av.y};
    h16x2 a23 = {(_Float16)av.z, (_Float16)av.w};
    const h16x2 neg2 = {(_Float16)NEG, (_Float16)NEG};

    int beg = rowptr[v];
    int end = rowptr[v + 1];

    float lrun = 0.f;
    float4 acc = make_float4(0.f, 0.f, 0.f, 0.f);

    auto proc = [&](float2 raw, bool ok) {
        h16x2 h01 = *(h16x2*)&raw.x;
        h16x2 h23 = *(h16x2*)&raw.y;
        h16x2 s01 = h01 + rx01;
        h16x2 s23 = h23 + rx23;
        h16x2 l01 = __builtin_elementwise_max(s01, s01 * neg2);
        h16x2 l23 = __builtin_elementwise_max(s23, s23 * neg2);
        float part = dot4_h(l01, l23, a01, a23);
        part += __shfl_xor(part, 1);
        part += __shfl_xor(part, 2);
        float p = ok ? __expf(part) : 0.f;
        lrun += p;
        acc.x = fmaf(p, (float)h01.x, acc.x);
        acc.y = fmaf(p, (float)h01.y, acc.y);
        acc.z = fmaf(p, (float)h23.x, acc.z);
        acc.w = fmaf(p, (float)h23.y, acc.w);
    };

    int e = beg;
    for (; e + 8 <= end; e += 8) {      // full batches: no masking at all
        float2 r[4];
#pragma unroll
        for (int j = 0; j < 4; j++) {
            int u = col[e + 2 * j + half];
            r[j] = *(const float2*)&xl[((size_t)u << 7) + ch];
        }
#pragma unroll
        for (int j = 0; j < 4; j++) proc(r[j], true);
    }
    for (; e < end; e += 4) {           // masked tail, 4-edge granularity
        float2 r[2];
        bool ok[2];
#pragma unroll
        for (int j = 0; j < 2; j++) {
            int idx = e + 2 * j + half;
            ok[j] = (idx < end);
            r[j] = make_float2(0.f, 0.f);
            if (ok[j]) {
                int u = col[idx];
                r[j] = *(const float2*)&xl[((size_t)u << 7) + ch];
            }
        }
#pragma unroll
        for (int j = 0; j < 2; j++) proc(r[j], ok[j]);
    }

    // combine the two 32-lane halves
    lrun += __shfl_xor(lrun, 32);
    acc.x += __shfl_xor(acc.x, 32);
    acc.y += __shfl_xor(acc.y, 32);
    acc.z += __shfl_xor(acc.z, 32);
    acc.w += __shfl_xor(acc.w, 32);

    if (half == 0) {
        float inv = 1.0f / lrun;
        float4 b4 = *(const float4*)&bias[ch];
        float o[4] = {fmaf(acc.x, inv, b4.x), fmaf(acc.y, inv, b4.y),
                      fmaf(acc.z, inv, b4.z), fmaf(acc.w, inv, b4.w)};
        float4 m4 = *(const float4*)&bm[ch];
        float4 v4 = *(const float4*)&bv[ch];
        float4 g4 = *(const float4*)&g[ch];
        float4 e4 = *(const float4*)&be[ch];
        float ms[4] = {m4.x, m4.y, m4.z, m4.w};
        float vs[4] = {v4.x, v4.y, v4.z, v4.w};
        float gs[4] = {g4.x, g4.y, g4.z, g4.w};
        float es[4] = {e4.x, e4.y, e4.z, e4.w};
        unsigned short h[4];
#pragma unroll
        for (int j = 0; j < 4; j++) {
            o[j] = (o[j] - ms[j]) * rsqrtf(vs[j] + BN_EPS) * gs[j] + es[j];
            o[j] = o[j] > 0.f ? o[j] : expm1f(o[j]);
            h[j] = __half_as_ushort(__float2half(o[j]));
        }
        *(ushort4*)&oh[(size_t)v * 128 + ch] = make_ushort4(h[0], h[1], h[2], h[3]);
    }
}

// ---------------- final aggregate, fp32, HC=16, writes d_out ----------------

__global__ __launch_bounds__(256) void agg_f(
    const float* __restrict__ xl, const float* __restrict__ xr,
    const int* __restrict__ rowptr, const int* __restrict__ col,
    const float* __restrict__ att, const float* __restrict__ bias,
    float* __restrict__ out, int n) {
    int v = (blockIdx.x * blockDim.x + threadIdx.x) >> 6;
    if (v >= n) return;
    int lane = threadIdx.x & 63;
    int slot = lane >> 2;        // 16 edge slots
    int L = lane & 3;
    int ch = 4 * L;

    float4 xrv = *(const float4*)&xr[(size_t)v * 16 + ch];
    float4 av = *(const float4*)&att[ch];
    int beg = rowptr[v];
    int end = rowptr[v + 1];

    float lrun = 0.f;
    float4 acc = make_float4(0.f, 0.f, 0.f, 0.f);

    for (int eb = beg; eb < end; eb += 16) {
        int idx = eb + slot;
        bool ok = (idx < end);
        float4 xv = make_float4(0.f, 0.f, 0.f, 0.f);
        if (ok) {
            int u = col[idx];
            xv = *(const float4*)&xl[((size_t)u << 4) + ch];
        }
        float s0 = xv.x + xrv.x; s0 = s0 > 0.f ? s0 : NEG * s0;
        float s1 = xv.y + xrv.y; s1 = s1 > 0.f ? s1 : NEG * s1;
        float s2 = xv.z + xrv.z; s2 = s2 > 0.f ? s2 : NEG * s2;
        float s3 = xv.w + xrv.w; s3 = s3 > 0.f ? s3 : NEG * s3;
        float part = fmaf(s0, av.x, fmaf(s1, av.y, fmaf(s2, av.z, s3 * av.w)));
        part += __shfl_xor(part, 1);
        part += __shfl_xor(part, 2);
        float p = ok ? __expf(part) : 0.f;
        lrun += p;
        acc.x = fmaf(p, xv.x, acc.x);
        acc.y = fmaf(p, xv.y, acc.y);
        acc.z = fmaf(p, xv.z, acc.z);
        acc.w = fmaf(p, xv.w, acc.w);
    }

#pragma unroll
    for (int d = 4; d < 64; d <<= 1) {
        lrun += __shfl_xor(lrun, d);
        acc.x += __shfl_xor(acc.x, d);
        acc.y += __shfl_xor(acc.y, d);
        acc.z += __shfl_xor(acc.z, d);
        acc.w += __shfl_xor(acc.w, d);
    }

    if (slot == 0) {
        float inv = 1.0f / lrun;
        float4 b4 = *(const float4*)&bias[ch];
        *(float4*)&out[(size_t)v * 16 + ch] =
            make_float4(fmaf(acc.x, inv, b4.x), fmaf(acc.y, inv, b4.y),
                        fmaf(acc.z, inv, b4.z), fmaf(acc.w, inv, b4.w));
    }
}

// ---------------- launch ----------------

extern "C" void kernel_launch(void* const* d_in, const int* in_sizes, int n_in,
                              void* d_out, int out_size, void* d_ws, size_t ws_size,
                              hipStream_t stream) {
    const float* x = (const float*)d_in[0];
    const int* ei = (const int*)d_in[1];
    const float* Wl[4] = {(const float*)d_in[2], (const float*)d_in[6],
                          (const float*)d_in[10], (const float*)d_in[14]};
    const float* Wr[4] = {(const float*)d_in[3], (const float*)d_in[7],
                          (const float*)d_in[11], (const float*)d_in[15]};
    const float* att[4] = {(const float*)d_in[4], (const float*)d_in[8],
                           (const float*)d_in[12], (const float*)d_in[16]};
    const float* bias[4] = {(const float*)d_in[5], (const float*)d_in[9],
                            (const float*)d_in[13], (const float*)d_in[17]};
    const float* g[3] = {(const float*)d_in[18], (const float*)d_in[22], (const float*)d_in[26]};
    const float* be[3] = {(const float*)d_in[19], (const float*)d_in[23], (const float*)d_in[27]};
    const float* bm[3] = {(const float*)d_in[20], (const float*)d_in[24], (const float*)d_in[28]};
    const float* bv[3] = {(const float*)d_in[21], (const float*)d_in[25], (const float*)d_in[29]};

    const int n = in_sizes[0] / 128;
    const int E = in_sizes[1] / 2;
    const int ET = E + n;

    char* p = (char*)d_ws;
    __half* xh = (__half*)p;           p += (size_t)n * 128 * 2;
    __half* xlh = (__half*)p;          p += (size_t)n * 128 * 2;
    __half* xrh = (__half*)p;          p += (size_t)n * 128 * 2;
    float* xl3 = (float*)p;            p += (size_t)n * 16 * 4;
    float* xr3 = (float*)p;            p += (size_t)n * 16 * 4;
    int* rowptr = (int*)p;            p += (size_t)(n + 1) * 4;
    int* cnt = (int*)p;               p += (size_t)n * 4;
    int* fill = (int*)p;              p += (size_t)n * 4;
    int* col = (int*)p;               p += (size_t)ET * 4;
    int* bsums = (int*)p;             p += 256;
    __half* pk[4];
    for (int i = 0; i < 3; i++) { pk[i] = (__half*)p; p += 4 * 16 * 512 * 2; }
    pk[3] = (__half*)p;               p += 4 * 2 * 512 * 2;

    (void)hipMemsetAsync(cnt, 0, (size_t)n * 4, stream);
    (void)hipMemsetAsync(fill, 0, (size_t)n * 4, stream);

    const int tb = 256;
    hist_kernel<<<(ET + tb - 1) / tb, tb, 0, stream>>>(ei, E, n, cnt);
    int nb = (n + 1023) / 1024;
    scan_block<<<nb, 1024, 0, stream>>>(cnt, rowptr, bsums, n);
    scan_bsums<<<1, 64, 0, stream>>>(bsums, nb);
    scan_add<<<nb, 1024, 0, stream>>>(rowptr, bsums, n);
    scatter_kernel<<<(ET + tb - 1) / tb, tb, 0, stream>>>(ei, E, n, rowptr, fill, col);

    pack_all<<<200, 64, 0, stream>>>(Wl[0], Wr[0], Wl[1], Wr[1], Wl[2], Wr[2],
                                     Wl[3], Wr[3], pk[0], pk[1], pk[2], pk[3]);

    const int gb64 = (n + 63) / 64;
    const int gemmBlocksSmall = ((n + 15) / 16 + 3) / 4;
    const int aggBlocks = (n + 3) / 4;    // 1 node per wave, 4 waves/block

    // layer 0: GEMM stages LDS straight from fp32 x (no convert pass)
    gemm_h_big<true><<<gb64, 256, 0, stream>>>(nullptr, x, pk[0], xlh, xrh, n);
    agg_h<<<aggBlocks, 256, 0, stream>>>(
        xlh, xrh, rowptr, col, att[0], bias[0], g[0], be[0], bm[0], bv[0], xh, n);
    for (int i = 1; i < 3; i++) {
        gemm_h_big<false><<<gb64, 256, 0, stream>>>(xh, nullptr, pk[i], xlh, xrh, n);
        agg_h<<<aggBlocks, 256, 0, stream>>>(
            xlh, xrh, rowptr, col, att[i], bias[i], g[i], be[i], bm[i], bv[i], xh, n);
    }
    gemm_h_small<<<gemmBlocksSmall, 256, 0, stream>>>(xh, pk[3], xl3, xr3, n);
    agg_f<<<aggBlocks, 256, 0, stream>>>(
        xl3, xr3, rowptr, col, att[3], bias[3], (float*)d_out, n);
}

// Round 17
// 364.346 us; speedup vs baseline: 3.5090x; 1.0285x over previous
//
#include <hip/hip_runtime.h>
#include <hip/hip_fp16.h>
#include <math.h>

static constexpr float BN_EPS = 1e-5f;
static constexpr float NEG = 0.2f;

typedef float f32x4 __attribute__((ext_vector_type(4)));
typedef _Float16 h16x2 __attribute__((ext_vector_type(2)));
typedef _Float16 h16x8 __attribute__((ext_vector_type(8)));

// ---------------- hist + W-pack fused (independent work, chain start) --------
// blocks 0..191: pack layers 0-2 (NTT=16, M=128); 192..199: pack layer 3
// (NTT=2, M=16); blocks 200+: dst histogram (self-loop for e >= E).

__global__ __launch_bounds__(256) void hist_pack(
    const int* __restrict__ ei, int E, int n, int* __restrict__ cnt,
    const float* __restrict__ W0l, const float* __restrict__ W0r,
    const float* __restrict__ W1l, const float* __restrict__ W1r,
    const float* __restrict__ W2l, const float* __restrict__ W2r,
    const float* __restrict__ W3l, const float* __restrict__ W3r,
    __half* __restrict__ pk0, __half* __restrict__ pk1,
    __half* __restrict__ pk2, __half* __restrict__ pk3) {
    int b = blockIdx.x;
    if (b < 200) {
        if (threadIdx.x >= 64) return;
        const float *Wl, *Wr;
        __half* packed;
        int tile, NTT, M;
        if (b < 192) {
            int layer = b >> 6;
            tile = b & 63;
            NTT = 16; M = 128;
            Wl = (layer == 0) ? W0l : (layer == 1) ? W1l : W2l;
            Wr = (layer == 0) ? W0r : (layer == 1) ? W1r : W2r;
            packed = (layer == 0) ? pk0 : (layer == 1) ? pk1 : pk2;
        } else {
            tile = b - 192;
            NTT = 2; M = 16;
            Wl = W3l; Wr = W3r; packed = pk3;
        }
        int NT = NTT >> 1;
        int gnt = tile % NTT;
        int kt = tile / NTT;
        int l = threadIdx.x;
        const float* W = (gnt < NT) ? Wl : Wr;
        int col = (gnt % NT) * 16 + (l & 15);
        int krow = kt * 32 + ((l >> 4) << 3);
        size_t base = (size_t)tile * 512 + (size_t)l * 8;
#pragma unroll
        for (int j = 0; j < 8; j++)
            packed[base + j] = __float2half(W[(size_t)(krow + j) * M + col]);
    } else {
        int e = (b - 200) * 256 + threadIdx.x;
        int ET = E + n;
        if (e >= ET) return;
        int d = (e < E) ? ei[E + e] : (e - E);
        atomicAdd(&cnt[d], 1);
    }
}

// ---------------- CSR scan chain (R11-proven; grid.sync measured ~190us/
// barrier at 2048 blocks in R15 — kernel boundaries are the cheap barrier) ----

__global__ void scan_block(const int* __restrict__ cnt, int* __restrict__ rowptr,
                           int* __restrict__ bsums, int n) {
    __shared__ int s[1024];
    int i = blockIdx.x * 1024 + threadIdx.x;
    int vv = (i < n) ? cnt[i] : 0;
    s[threadIdx.x] = vv;
    __syncthreads();
    for (int d = 1; d < 1024; d <<= 1) {
        int t = (threadIdx.x >= d) ? s[threadIdx.x - d] : 0;
        __syncthreads();
        s[threadIdx.x] += t;
        __syncthreads();
    }
    if (i < n) rowptr[i + 1] = s[threadIdx.x];
    if (threadIdx.x == 1023) bsums[blockIdx.x] = s[1023];
}

__global__ void scan_bsums(int* __restrict__ bsums, int nb) {
    int L = threadIdx.x;
    int v = (L < nb) ? bsums[L] : 0;
    for (int d = 1; d < 64; d <<= 1) {
        int t = __shfl_up(v, d);
        if (L >= d) v += t;
    }
    int ex = __shfl_up(v, 1);
    if (L == 0) ex = 0;
    if (L < nb) bsums[L] = ex;
}

__global__ void scan_add(int* __restrict__ rowptr, const int* __restrict__ bsums, int n) {
    int i = blockIdx.x * 1024 + threadIdx.x;
    if (i < n) rowptr[i + 1] += bsums[blockIdx.x];
    if (i == 0) rowptr[0] = 0;
}

__global__ void scatter_kernel(const int* __restrict__ ei, int E, int n,
                               const int* __restrict__ rowptr, int* __restrict__ fill,
                               int* __restrict__ col) {
    int e = blockIdx.x * blockDim.x + threadIdx.x;
    int ET = E + n;
    if (e >= ET) return;
    int s, d;
    if (e < E) { s = ei[e]; d = ei[E + e]; } else { s = e - E; d = s; }
    int pos = atomicAdd(&fill[d], 1);
    col[rowptr[d] + pos] = s;
}

// ---------------- fp16 MFMA dual GEMM: Y1 = X@Wl, Y2 = X@Wr (M=128 each) ----

template <bool FIRST>
__global__ __launch_bounds__(256) void gemm_h_big(
    const __half* __restrict__ xh, const float* __restrict__ xf,
    const __half* __restrict__ packed,
    __half* __restrict__ Y1, __half* __restrict__ Y2, int n) {
    __shared__ _Float16 sA[64 * 136];
    const int t = threadIdx.x;
    const int row0 = blockIdx.x * 64;

    for (int c = t; c < 1024; c += 256) {
        int row = c >> 4;
        int off = (c & 15) * 8;
        int gr = row0 + row;
        if (gr >= n) gr = n - 1;
        if (FIRST) {
            float4 v0 = *(const float4*)&xf[(size_t)gr * 128 + off];
            float4 v1 = *(const float4*)&xf[(size_t)gr * 128 + off + 4];
            h16x8 h = {(_Float16)v0.x, (_Float16)v0.y, (_Float16)v0.z, (_Float16)v0.w,
                       (_Float16)v1.x, (_Float16)v1.y, (_Float16)v1.z, (_Float16)v1.w};
            *(h16x8*)&sA[row * 136 + off] = h;
        } else {
            *(h16x8*)&sA[row * 136 + off] = *(const h16x8*)&xh[(size_t)gr * 128 + off];
        }
    }
    __syncthreads();

    const int lane = t & 63;
    const int s = t >> 6;
    const int lr = lane & 15;
    const int kq = (lane >> 4) * 8;

    h16x8 af[4][4];                 // [rt][kt]
#pragma unroll
    for (int rt = 0; rt < 4; rt++)
#pragma unroll
        for (int kt = 0; kt < 4; kt++)
            af[rt][kt] = *(const h16x8*)&sA[(rt * 16 + lr) * 136 + kt * 32 + kq];

    f32x4 acc[4][4];                // [ntl][rt]
#pragma unroll
    for (int a = 0; a < 4; a++)
#pragma unroll
        for (int b = 0; b < 4; b++) acc[a][b] = (f32x4){0.f, 0.f, 0.f, 0.f};

#pragma unroll
    for (int kt = 0; kt < 4; kt++) {
#pragma unroll
        for (int ntl = 0; ntl < 4; ntl++) {
            int nt = s * 4 + ntl;
            h16x8 b = *(const h16x8*)&packed[((size_t)(kt * 16 + nt)) * 512 + lane * 8];
#pragma unroll
            for (int rt = 0; rt < 4; rt++)
                acc[ntl][rt] = __builtin_amdgcn_mfma_f32_16x16x32_f16(af[rt][kt], b, acc[ntl][rt], 0, 0, 0);
        }
    }

    __half* Y = (s < 2) ? Y1 : Y2;
    const int colh = (s & 1) * 64;
    const int rq = (lane >> 4) * 4;
#pragma unroll
    for (int ntl = 0; ntl < 4; ntl++) {
        int col = colh + ntl * 16 + lr;
#pragma unroll
        for (int rt = 0; rt < 4; rt++) {
#pragma unroll
            for (int g = 0; g < 4; g++) {
                int row = row0 + rt * 16 + rq + g;
                if (row < n) Y[(size_t)row * 128 + col] = __float2half(acc[ntl][rt][g]);
            }
        }
    }
}

// ---------------- small fp16 GEMM for layer 3 (M=16 each, fp32 out) ----------

__global__ __launch_bounds__(256) void gemm_h_small(
    const __half* __restrict__ xh, const __half* __restrict__ packed,
    float* __restrict__ Y1, float* __restrict__ Y2, int n) {
    int lane = threadIdx.x & 63;
    int wv = blockIdx.x * 4 + (threadIdx.x >> 6);
    int row0 = wv * 16;
    if (row0 >= n) return;
    int r = row0 + (lane & 15);
    if (r >= n) r = n - 1;
    int kq = (lane >> 4) * 8;

    h16x8 af[4];
#pragma unroll
    for (int kt = 0; kt < 4; kt++)
        af[kt] = *(const h16x8*)&xh[(size_t)r * 128 + kt * 32 + kq];

    f32x4 acc[2];
    acc[0] = (f32x4){0.f, 0.f, 0.f, 0.f};
    acc[1] = (f32x4){0.f, 0.f, 0.f, 0.f};

#pragma unroll
    for (int kt = 0; kt < 4; kt++) {
#pragma unroll
        for (int nt = 0; nt < 2; nt++) {
            h16x8 b = *(const h16x8*)&packed[((size_t)(kt * 2 + nt)) * 512 + lane * 8];
            acc[nt] = __builtin_amdgcn_mfma_f32_16x16x32_f16(af[kt], b, acc[nt], 0, 0, 0);
        }
    }

    int colb = lane & 15;
    int rbase = row0 + (lane >> 4) * 4;
#pragma unroll
    for (int nt = 0; nt < 2; nt++) {
        float* Y = (nt == 0) ? Y1 : Y2;
#pragma unroll
        for (int g = 0; g < 4; g++) {
            int row = rbase + g;
            if (row < n) Y[(size_t)row * 16 + colb] = acc[nt][g];
        }
    }
}

// ---------------- Fused GATv2 aggregate (R11-proven 2-edge form) ------------

__device__ __forceinline__ float dot4_h(h16x2 l01, h16x2 l23,
                                        h16x2 a01, h16x2 a23) {
#if __has_builtin(__builtin_amdgcn_fdot2)
    float part = __builtin_amdgcn_fdot2(l01, a01, 0.f, false);
    return __builtin_amdgcn_fdot2(l23, a23, part, false);
#else
    return fmaf((float)l01.x, (float)a01.x, fmaf((float)l01.y, (float)a01.y,
           fmaf((float)l23.x, (float)a23.x, (float)l23.y * (float)a23.y)));
#endif
}

__global__ __launch_bounds__(256) void agg_h(
    const __half* __restrict__ xl, const __half* __restrict__ xr,
    const int* __restrict__ rowptr, const int* __restrict__ col,
    const float* __restrict__ att, const float* __restrict__ bias,
    const float* __restrict__ g, const float* __restrict__ be,
    const float* __restrict__ bm, const float* __restrict__ bv,
    __half* __restrict__ oh, int n) {
    int v = (blockIdx.x * blockDim.x + threadIdx.x) >> 6;
    if (v >= n) return;
    int lane = threadIdx.x & 63;
    int half = lane >> 5;
    int L = lane & 31;
    int ch = 4 * L;

    float2 rraw = *(const float2*)&xr[(size_t)v * 128 + ch];
    h16x2 rx01 = *(h16x2*)&rraw.x;
    h16x2 rx23 = *(h16x2*)&rraw.y;
    float4 av = *(const float4*)&att[ch];
    h16x2 a01 = {(_Float16)av.x, (_Float16)av.y};
    h16x2 a23 = {(_Float16)av.z, (_Float16)av.w};
    const h16x2 neg2 = {(_Float16)NEG, (_Float16)NEG};

    int beg = rowptr[v];
    int end = rowptr[v + 1];

    float lrun = 0.f;
    float4 acc = make_float4(0.f, 0.f, 0.f, 0.f);

    auto proc = [&](float2 raw, bool ok) {
        h16x2 h01 = *(h16x2*)&raw.x;
        h16x2 h23 = *(h16x2*)&raw.y;
        h16x2 s01 = h01 + rx01;
        h16x2 s23 = h23 + rx23;
        h16x2 l01 = __builtin_elementwise_max(s01, s01 * neg2);
        h16x2 l23 = __builtin_elementwise_max(s23, s23 * neg2);
        float part = dot4_h(l01, l23, a01, a23);
        part += __shfl_xor(part, 1);
        part += __shfl_xor(part, 2);
        float p = ok ? __expf(part) : 0.f;
        lrun += p;
        acc.x = fmaf(p, (float)h01.x, acc.x);
        acc.y = fmaf(p, (float)h01.y, acc.y);
        acc.z = fmaf(p, (float)h23.x, acc.z);
        acc.w = fmaf(p, (float)h23.y, acc.w);
    };

    int e = beg;
    for (; e + 8 <= end; e += 8) {      // full batches: no masking at all
        float2 r[4];
#pragma unroll
        for (int j = 0; j < 4; j++) {
            int u = col[e + 2 * j + half];
            r[j] = *(const float2*)&xl[((size_t)u << 7) + ch];
        }
#pragma unroll
        for (int j = 0; j < 4; j++) proc(r[j], true);
    }
    for (; e < end; e += 4) {           // masked tail, 4-edge granularity
        float2 r[2];
        bool ok[2];
#pragma unroll
        for (int j = 0; j < 2; j++) {
            int idx = e + 2 * j + half;
            ok[j] = (idx < end);
            r[j] = make_float2(0.f, 0.f);
            if (ok[j]) {
                int u = col[idx];
                r[j] = *(const float2*)&xl[((size_t)u << 7) + ch];
            }
        }
#pragma unroll
        for (int j = 0; j < 2; j++) proc(r[j], ok[j]);
    }

    // combine the two 32-lane halves
    lrun += __shfl_xor(lrun, 32);
    acc.x += __shfl_xor(acc.x, 32);
    acc.y += __shfl_xor(acc.y, 32);
    acc.z += __shfl_xor(acc.z, 32);
    acc.w += __shfl_xor(acc.w, 32);

    if (half == 0) {
        float inv = 1.0f / lrun;
        float4 b4 = *(const float4*)&bias[ch];
        float o[4] = {fmaf(acc.x, inv, b4.x), fmaf(acc.y, inv, b4.y),
                      fmaf(acc.z, inv, b4.z), fmaf(acc.w, inv, b4.w)};
        float4 m4 = *(const float4*)&bm[ch];
        float4 v4 = *(const float4*)&bv[ch];
        float4 g4 = *(const float4*)&g[ch];
        float4 e4 = *(const float4*)&be[ch];
        float ms[4] = {m4.x, m4.y, m4.z, m4.w};
        float vs[4] = {v4.x, v4.y, v4.z, v4.w};
        float gs[4] = {g4.x, g4.y, g4.z, g4.w};
        float es[4] = {e4.x, e4.y, e4.z, e4.w};
        unsigned short h[4];
#pragma unroll
        for (int j = 0; j < 4; j++) {
            o[j] = (o[j] - ms[j]) * rsqrtf(vs[j] + BN_EPS) * gs[j] + es[j];
            o[j] = o[j] > 0.f ? o[j] : expm1f(o[j]);
            h[j] = __half_as_ushort(__float2half(o[j]));
        }
        *(ushort4*)&oh[(size_t)v * 128 + ch] = make_ushort4(h[0], h[1], h[2], h[3]);
    }
}

// ---------------- final aggregate, fp32, HC=16, writes d_out ----------------

__global__ __launch_bounds__(256) void agg_f(
    const float* __restrict__ xl, const float* __restrict__ xr,
    const int* __restrict__ rowptr, const int* __restrict__ col,
    const float* __restrict__ att, const float* __restrict__ bias,
    float* __restrict__ out, int n) {
    int v = (blockIdx.x * blockDim.x + threadIdx.x) >> 6;
    if (v >= n) return;
    int lane = threadIdx.x & 63;
    int slot = lane >> 2;        // 16 edge slots
    int L = lane & 3;
    int ch = 4 * L;

    float4 xrv = *(const float4*)&xr[(size_t)v * 16 + ch];
    float4 av = *(const float4*)&att[ch];
    int beg = rowptr[v];
    int end = rowptr[v + 1];

    float lrun = 0.f;
    float4 acc = make_float4(0.f, 0.f, 0.f, 0.f);

    for (int eb = beg; eb < end; eb += 16) {
        int idx = eb + slot;
        bool ok = (idx < end);
        float4 xv = make_float4(0.f, 0.f, 0.f, 0.f);
        if (ok) {
            int u = col[idx];
            xv = *(const float4*)&xl[((size_t)u << 4) + ch];
        }
        float s0 = xv.x + xrv.x; s0 = s0 > 0.f ? s0 : NEG * s0;
        float s1 = xv.y + xrv.y; s1 = s1 > 0.f ? s1 : NEG * s1;
        float s2 = xv.z + xrv.z; s2 = s2 > 0.f ? s2 : NEG * s2;
        float s3 = xv.w + xrv.w; s3 = s3 > 0.f ? s3 : NEG * s3;
        float part = fmaf(s0, av.x, fmaf(s1, av.y, fmaf(s2, av.z, s3 * av.w)));
        part += __shfl_xor(part, 1);
        part += __shfl_xor(part, 2);
        float p = ok ? __expf(part) : 0.f;
        lrun += p;
        acc.x = fmaf(p, xv.x, acc.x);
        acc.y = fmaf(p, xv.y, acc.y);
        acc.z = fmaf(p, xv.z, acc.z);
        acc.w = fmaf(p, xv.w, acc.w);
    }

#pragma unroll
    for (int d = 4; d < 64; d <<= 1) {
        lrun += __shfl_xor(lrun, d);
        acc.x += __shfl_xor(acc.x, d);
        acc.y += __shfl_xor(acc.y, d);
        acc.z += __shfl_xor(acc.z, d);
        acc.w += __shfl_xor(acc.w, d);
    }

    if (slot == 0) {
        float inv = 1.0f / lrun;
        float4 b4 = *(const float4*)&bias[ch];
        *(float4*)&out[(size_t)v * 16 + ch] =
            make_float4(fmaf(acc.x, inv, b4.x), fmaf(acc.y, inv, b4.y),
                        fmaf(acc.z, inv, b4.z), fmaf(acc.w, inv, b4.w));
    }
}

// ---------------- launch ----------------

extern "C" void kernel_launch(void* const* d_in, const int* in_sizes, int n_in,
                              void* d_out, int out_size, void* d_ws, size_t ws_size,
                              hipStream_t stream) {
    const float* x = (const float*)d_in[0];
    const int* ei = (const int*)d_in[1];
    const float* Wl[4] = {(const float*)d_in[2], (const float*)d_in[6],
                          (const float*)d_in[10], (const float*)d_in[14]};
    const float* Wr[4] = {(const float*)d_in[3], (const float*)d_in[7],
                          (const float*)d_in[11], (const float*)d_in[15]};
    const float* att[4] = {(const float*)d_in[4], (const float*)d_in[8],
                           (const float*)d_in[12], (const float*)d_in[16]};
    const float* bias[4] = {(const float*)d_in[5], (const float*)d_in[9],
                            (const float*)d_in[13], (const float*)d_in[17]};
    const float* g[3] = {(const float*)d_in[18], (const float*)d_in[22], (const float*)d_in[26]};
    const float* be[3] = {(const float*)d_in[19], (const float*)d_in[23], (const float*)d_in[27]};
    const float* bm[3] = {(const float*)d_in[20], (const float*)d_in[24], (const float*)d_in[28]};
    const float* bv[3] = {(const float*)d_in[21], (const float*)d_in[25], (const float*)d_in[29]};

    const int n = in_sizes[0] / 128;
    const int E = in_sizes[1] / 2;
    const int ET = E + n;

    char* p = (char*)d_ws;
    __half* xh = (__half*)p;           p += (size_t)n * 128 * 2;
    __half* xlh = (__half*)p;          p += (size_t)n * 128 * 2;
    __half* xrh = (__half*)p;          p += (size_t)n * 128 * 2;
    float* xl3 = (float*)p;            p += (size_t)n * 16 * 4;
    float* xr3 = (float*)p;            p += (size_t)n * 16 * 4;
    int* rowptr = (int*)p;            p += (size_t)(n + 1) * 4;
    int* cnt = (int*)p;               p += (size_t)n * 4;
    int* fill = (int*)p;              p += (size_t)n * 4;   // contiguous after cnt
    int* col = (int*)p;               p += (size_t)ET * 4;
    int* bsums = (int*)p;             p += 256;
    __half* pk[4];
    for (int i = 0; i < 3; i++) { pk[i] = (__half*)p; p += 4 * 16 * 512 * 2; }
    pk[3] = (__half*)p;               p += 4 * 2 * 512 * 2;

    // one memset over cnt+fill (adjacent, 8n bytes)
    (void)hipMemsetAsync(cnt, 0, (size_t)n * 8, stream);

    const int tb = 256;
    const int histBlocks = (ET + tb - 1) / tb;
    hist_pack<<<200 + histBlocks, tb, 0, stream>>>(
        ei, E, n, cnt,
        Wl[0], Wr[0], Wl[1], Wr[1], Wl[2], Wr[2], Wl[3], Wr[3],
        pk[0], pk[1], pk[2], pk[3]);
    int nb = (n + 1023) / 1024;
    scan_block<<<nb, 1024, 0, stream>>>(cnt, rowptr, bsums, n);
    scan_bsums<<<1, 64, 0, stream>>>(bsums, nb);
    scan_add<<<nb, 1024, 0, stream>>>(rowptr, bsums, n);
    scatter_kernel<<<(ET + tb - 1) / tb, tb, 0, stream>>>(ei, E, n, rowptr, fill, col);

    const int gb64 = (n + 63) / 64;
    const int gemmBlocksSmall = ((n + 15) / 16 + 3) / 4;
    const int aggBlocks = (n + 3) / 4;    // 1 node per wave, 4 waves/block

    // layer 0: GEMM stages LDS straight from fp32 x (no convert pass)
    gemm_h_big<true><<<gb64, 256, 0, stream>>>(nullptr, x, pk[0], xlh, xrh, n);
    agg_h<<<aggBlocks, 256, 0, stream>>>(
        xlh, xrh, rowptr, col, att[0], bias[0], g[0], be[0], bm[0], bv[0], xh, n);
    for (int i = 1; i < 3; i++) {
        gemm_h_big<false><<<gb64, 256, 0, stream>>>(xh, nullptr, pk[i], xlh, xrh, n);
        agg_h<<<aggBlocks, 256, 0, stream>>>(
            xlh, xrh, rowptr, col, att[i], bias[i], g[i], be[i], bm[i], bv[i], xh, n);
    }
    gemm_h_small<<<gemmBlocksSmall, 256, 0, stream>>>(xh, pk[3], xl3, xr3, n);
    agg_f<<<aggBlocks, 256, 0, stream>>>(
        xl3, xr3, rowptr, col, att[3], bias[3], (float*)d_out, n);
}